// Round 5
// baseline (5350.872 us; speedup 1.0000x reference)
//
#include <hip/hip_runtime.h>
#include <hip/hip_bf16.h>

// TrajectoryDecoder: 2-layer LSTM (H=256), 45 steps, B=4096.
// R5: weights repacked ONCE to bf16 MFMA-B-tiles in d_ws (1.57 MB).
//   Tile (ut,g,kt) = 16 gate-units x 32 k, stored lane-major: one
//   global_load_dwordx4 per B-fragment at base+lane*16 (coalesced,
//   sequential sweep). gctx hoisted to registers (const across steps).
// 256 WGs x BB=16 batches, 512 threads (8 waves, 2/SIMD), persistent.
// mfma_f32_16x16x32_bf16 (m97-verified):
//   A: row=lane&15 (batch), k=(lane>>4)*8+j ; B: col=lane&15 (gate unit)
//   C/D: row=(lane>>4)*4+q (batch), col=lane&15 (gate unit)

#define BB    16
#define TPB   512
#define HN    256
#define DM    128
#define NSTEP 45

typedef __attribute__((ext_vector_type(8))) short s8v;
typedef __attribute__((ext_vector_type(4))) float f32x4;

#define MFMA16(a,b,c) __builtin_amdgcn_mfma_f32_16x16x32_bf16((a),(b),(c),0,0,0)

// d_ws layout (ushort units):
//  Whh0 tiles [ut16][g4][kt8][lane64][8] : 262144
//  Wih1 tiles                            : 262144 (base 262144)
//  Whh1 tiles                            : 262144 (base 524288)
//  Wp1  tiles [ut4][kt8][lane64][8]      : 16384  (base 786432)

__device__ __forceinline__ unsigned short f2bf(float f){
  union { float f; unsigned u; } x; x.f = f;
  unsigned r = x.u + 0x7fffu + ((x.u >> 16) & 1u);
  return (unsigned short)(r >> 16);
}
__device__ __forceinline__ float sigm(float x){
  x = fminf(40.f, fmaxf(-40.f, x));
  return 1.f/(1.f + __expf(-x));
}
__device__ __forceinline__ float tanhx(float x){
  float xx = fminf(15.f, fmaxf(-15.f, x));
  float e = __expf(2.f*xx);
  return (e-1.f)/(e+1.f);
}

// h LDS: bf16 [16 rows][256], row b element u stored at u ^ ((b&7)<<3)
__device__ __forceinline__ void write_h(unsigned short* lds, int b, int u, float v){
  lds[b*HN + (u ^ ((b&7)<<3))] = f2bf(v);
}
__device__ __forceinline__ s8v read_afrag(const unsigned short* lds, int b, int hi, int kt){
  int blk = (kt*4 + hi) ^ (b & 7);
  return *(const s8v*)(lds + b*HN + blk*8);
}

// ---- repack: fp32 row-major -> bf16 B-fragment tiles ----
__global__ void repack(const float* __restrict__ Whh0, const float* __restrict__ Wih1,
                       const float* __restrict__ Whh1, const float* __restrict__ Wp1,
                       unsigned short* __restrict__ dst){
  int gid  = blockIdx.x*256 + threadIdx.x;   // 100352 threads, one per 8 elems
  int lane = gid & 63;
  int tile = gid >> 6;                       // 0..1567
  const float* src; int row; size_t doff;
  int k0 = (lane>>4)*8;
  if (tile < 1536){
    int mi = tile / 512;        // matrix index
    int r  = tile % 512;        // (ut*4+g)*8 + kt
    int kt = r & 7;
    int gu = r >> 3;            // ut*4+g
    int g  = gu & 3, ut = gu >> 2;
    src  = (mi==0) ? Whh0 : (mi==1) ? Wih1 : Whh1;
    row  = g*256 + ut*16 + (lane&15);
    k0  += kt*32;
    doff = (size_t)mi*262144 + (size_t)r*512 + lane*8;
  } else {
    int r2 = tile - 1536;       // ut*8 + kt
    int kt = r2 & 7, ut = r2 >> 3;
    src  = Wp1;
    row  = ut*16 + (lane&15);
    k0  += kt*32;
    doff = 786432 + (size_t)r2*512 + lane*8;
  }
  const float* s = src + (size_t)row*HN + k0;
  float4 a = *(const float4*)(s);
  float4 b = *(const float4*)(s+4);
  unsigned short* d = dst + doff;
  d[0]=f2bf(a.x); d[1]=f2bf(a.y); d[2]=f2bf(a.z); d[3]=f2bf(a.w);
  d[4]=f2bf(b.x); d[5]=f2bf(b.y); d[6]=f2bf(b.z); d[7]=f2bf(b.w);
}

__global__ __launch_bounds__(TPB, 2)
void traj_mfma(const float* __restrict__ enc,   // B x 128
               const float* __restrict__ pos0,  // B x 2
               const float* __restrict__ ctx,   // B x 128
               const float* __restrict__ Wh,    // 512 x 128
               const float* __restrict__ bh,
               const float* __restrict__ Wc,
               const float* __restrict__ bc,
               const float* __restrict__ Wih0,  // 1024 x 130
               const float* __restrict__ bih0,
               const float* __restrict__ bhh0,
               const float* __restrict__ bih1,
               const float* __restrict__ bhh1,
               const float* __restrict__ Wp2,   // 2 x 64
               const float* __restrict__ bp1,
               const float* __restrict__ bp2,
               const unsigned short* __restrict__ wsW,
               float* __restrict__ out)         // B x 45 x 2
{
  __shared__ float sh_gctx[BB][4*HN];          // 64KB staging (read once)
  __shared__ unsigned short sh_h0u[BB*HN];     // 8KB bf16 swizzled
  __shared__ unsigned short sh_h1u[BB*HN];     // 8KB
  __shared__ float sh_ct0[BB][HN];             // 16KB (init handoff)
  __shared__ float sh_ct1[BB][HN];             // 16KB
  __shared__ float sh_x[BB][DM];               // 8KB staging
  __shared__ float sh_pos[BB][2];
  __shared__ float sh_red[4][BB][2];

  const int tid  = threadIdx.x;
  const int gb0  = blockIdx.x * BB;
  const int lane = tid & 63;
  const int w    = tid >> 6;        // 8 waves
  const int col  = lane & 15;
  const int hi   = lane >> 4;

  // ---- stage encoder_feat + pos ----
  {
    const float4* src = (const float4*)(enc + (size_t)gb0*DM);
    ((float4*)&sh_x[0][0])[tid] = src[tid];
  }
  if (tid < BB*2) ((float*)sh_pos)[tid] = pos0[(size_t)gb0*2 + tid];
  __syncthreads();

  // ---- h/c init: thread r computes h_all/c_all row r ----
  {
    const int r = tid;
    float ah[BB], ac[BB];
    #pragma unroll
    for (int b=0;b<BB;b++){ ah[b]=0.f; ac[b]=0.f; }
    const float4* whr = (const float4*)(Wh + (size_t)r*DM);
    const float4* wcr = (const float4*)(Wc + (size_t)r*DM);
    #pragma nounroll
    for (int kk=0; kk<DM/4; kk++){
      float4 w0 = whr[kk], w1 = wcr[kk];
      #pragma unroll
      for (int b=0;b<BB;b++){
        float4 x = *(const float4*)&sh_x[b][kk*4];
        ah[b] += w0.x*x.x + w0.y*x.y + w0.z*x.z + w0.w*x.w;
        ac[b] += w1.x*x.x + w1.y*x.y + w1.z*x.z + w1.w*x.w;
      }
    }
    float bhv = bh[r], bcv = bc[r];
    if (r < HN){
      #pragma unroll
      for (int b=0;b<BB;b++){
        write_h(sh_h0u, b, r, ah[b] + bhv);
        sh_ct0[b][r] = ac[b] + bcv;
      }
    } else {
      #pragma unroll
      for (int b=0;b<BB;b++){
        write_h(sh_h1u, b, r-HN, ah[b] + bhv);
        sh_ct1[b][r-HN] = ac[b] + bcv;
      }
    }
  }
  __syncthreads();

  // ---- stage context ----
  {
    const float4* src = (const float4*)(ctx + (size_t)gb0*DM);
    ((float4*)&sh_x[0][0])[tid] = src[tid];
  }
  __syncthreads();

  // ---- gates_ctx (fp32): thread handles gate rows tid and tid+512 ----
  {
    float a0[BB], a1[BB];
    #pragma unroll
    for (int b=0;b<BB;b++){ a0[b]=0.f; a1[b]=0.f; }
    const float2* wr0 = (const float2*)(Wih0 + (size_t)tid*130 + 2);
    const float2* wr1 = (const float2*)(Wih0 + (size_t)(tid+512)*130 + 2);
    #pragma nounroll
    for (int kk=0; kk<DM/2; kk++){
      float2 w0 = wr0[kk], w1 = wr1[kk];
      #pragma unroll
      for (int b=0;b<BB;b++){
        float2 x = *(const float2*)&sh_x[b][kk*2];
        a0[b] += w0.x*x.x + w0.y*x.y;
        a1[b] += w1.x*x.x + w1.y*x.y;
      }
    }
    float c0 = bih0[tid]     + bhh0[tid];
    float c1 = bih0[tid+512] + bhh0[tid+512];
    #pragma unroll
    for (int b=0;b<BB;b++){
      sh_gctx[b][tid]     = a0[b] + c0;
      sh_gctx[b][tid+512] = a1[b] + c1;
    }
  }

  // ---- per-lane constants ----
  float wpr[2][4][2]; float b1r[2][4];
  #pragma unroll
  for (int m=0;m<2;m++){
    int uu = (w*2+m)*16 + col;
    #pragma unroll
    for (int g=0;g<4;g++){
      int j = (g<<8) + uu;
      wpr[m][g][0] = Wih0[(size_t)j*130 + 0];
      wpr[m][g][1] = Wih0[(size_t)j*130 + 1];
      b1r[m][g]    = bih1[j] + bhh1[j];
    }
  }
  const int   p    = (w&3)*16 + col;
  const float bp1p = bp1[p], w20 = Wp2[p], w21 = Wp2[64+p];
  const float bp20 = bp2[0], bp21 = bp2[1];
  __syncthreads();   // gctx + sh_ct complete

  // ---- hoist gctx + c-state into registers (const across steps / state) ----
  float greg[2][4][4];   // [m][g][q]
  float c0r[2][4], c1r[2][4];
  #pragma unroll
  for (int m=0;m<2;m++){
    int uu = (w*2+m)*16 + col;
    #pragma unroll
    for (int q=0;q<4;q++){
      int b = hi*4+q;
      #pragma unroll
      for (int g=0;g<4;g++) greg[m][g][q] = sh_gctx[b][(g<<8) + uu];
      c0r[m][q] = sh_ct0[b][uu];
      c1r[m][q] = sh_ct1[b][uu];
    }
  }

  // tile bases (ushort units) for this wave
  // Whh0: (ut*4+g)*4096 + kt*512 + lane*8
  const unsigned short* wT0 = wsW;            // Whh0
  const unsigned short* wT1 = wsW + 262144;   // Wih1
  const unsigned short* wT2 = wsW + 524288;   // Whh1
  const unsigned short* wTp = wsW + 786432;   // Wp1

  // ================= 45-step rollout =================
  #pragma nounroll
  for (int t=0; t<NSTEP; t++){
    // ---- P1: A-frags of h0,h1 + pos ----
    s8v a0[8], a1[8];
    #pragma unroll
    for (int kt=0;kt<8;kt++){
      a0[kt] = read_afrag(sh_h0u, col, hi, kt);
      a1[kt] = read_afrag(sh_h1u, col, hi, kt);
    }
    float p0q[4], p1q[4];
    #pragma unroll
    for (int q=0;q<4;q++){
      float2 pp = *(const float2*)&sh_pos[hi*4+q][0];
      p0q[q]=pp.x; p1q[q]=pp.y;
    }
    __syncthreads();

    // ---- P2: layer0 gates + cell ----
    #pragma unroll
    for (int m=0;m<2;m++){
      const int ut = w*2+m;
      const int uu = ut*16 + col;
      f32x4 ac0, ac1, ac2, ac3;
      #pragma unroll
      for (int q=0;q<4;q++){
        ac0[q] = greg[m][0][q] + p0q[q]*wpr[m][0][0] + p1q[q]*wpr[m][0][1];
        ac1[q] = greg[m][1][q] + p0q[q]*wpr[m][1][0] + p1q[q]*wpr[m][1][1];
        ac2[q] = greg[m][2][q] + p0q[q]*wpr[m][2][0] + p1q[q]*wpr[m][2][1];
        ac3[q] = greg[m][3][q] + p0q[q]*wpr[m][3][0] + p1q[q]*wpr[m][3][1];
      }
      const unsigned short* tb = wT0 + (size_t)(ut*4)*4096 + lane*8;
      #pragma unroll
      for (int kt=0;kt<8;kt++){
        ac0 = MFMA16(a0[kt], *(const s8v*)(tb +           kt*512), ac0);
        ac1 = MFMA16(a0[kt], *(const s8v*)(tb +  4096 +   kt*512), ac1);
        ac2 = MFMA16(a0[kt], *(const s8v*)(tb +  8192 +   kt*512), ac2);
        ac3 = MFMA16(a0[kt], *(const s8v*)(tb + 12288 +   kt*512), ac3);
      }
      #pragma unroll
      for (int q=0;q<4;q++){
        float iv = sigm(ac0[q]), fv = sigm(ac1[q]);
        float gv = tanhx(ac2[q]), ov = sigm(ac3[q]);
        float cv = fv*c0r[m][q] + iv*gv;
        c0r[m][q] = cv;
        write_h(sh_h0u, hi*4+q, uu, ov*tanhx(cv));
      }
    }
    __syncthreads();

    // ---- P3: layer1 gates + cell ----
    s8v a0n[8];
    #pragma unroll
    for (int kt=0;kt<8;kt++) a0n[kt] = read_afrag(sh_h0u, col, hi, kt);
    #pragma unroll
    for (int m=0;m<2;m++){
      const int ut = w*2+m;
      const int uu = ut*16 + col;
      f32x4 ac0 = {b1r[m][0],b1r[m][0],b1r[m][0],b1r[m][0]};
      f32x4 ac1 = {b1r[m][1],b1r[m][1],b1r[m][1],b1r[m][1]};
      f32x4 ac2 = {b1r[m][2],b1r[m][2],b1r[m][2],b1r[m][2]};
      f32x4 ac3 = {b1r[m][3],b1r[m][3],b1r[m][3],b1r[m][3]};
      const unsigned short* tb1 = wT1 + (size_t)(ut*4)*4096 + lane*8;
      const unsigned short* tb2 = wT2 + (size_t)(ut*4)*4096 + lane*8;
      #pragma unroll
      for (int kt=0;kt<8;kt++){
        ac0 = MFMA16(a0n[kt], *(const s8v*)(tb1 +           kt*512), ac0);
        ac1 = MFMA16(a0n[kt], *(const s8v*)(tb1 +  4096 +   kt*512), ac1);
        ac2 = MFMA16(a0n[kt], *(const s8v*)(tb1 +  8192 +   kt*512), ac2);
        ac3 = MFMA16(a0n[kt], *(const s8v*)(tb1 + 12288 +   kt*512), ac3);
      }
      #pragma unroll
      for (int kt=0;kt<8;kt++){
        ac0 = MFMA16(a1[kt], *(const s8v*)(tb2 +           kt*512), ac0);
        ac1 = MFMA16(a1[kt], *(const s8v*)(tb2 +  4096 +   kt*512), ac1);
        ac2 = MFMA16(a1[kt], *(const s8v*)(tb2 +  8192 +   kt*512), ac2);
        ac3 = MFMA16(a1[kt], *(const s8v*)(tb2 + 12288 +   kt*512), ac3);
      }
      #pragma unroll
      for (int q=0;q<4;q++){
        float iv = sigm(ac0[q]), fv = sigm(ac1[q]);
        float gv = tanhx(ac2[q]), ov = sigm(ac3[q]);
        float cv = fv*c1r[m][q] + iv*gv;
        c1r[m][q] = cv;
        write_h(sh_h1u, hi*4+q, uu, ov*tanhx(cv));
      }
    }
    __syncthreads();

    // ---- P4: head (waves 0..3 compute 64 p-units) ----
    if (w < 4){
      s8v a1n[8];
      #pragma unroll
      for (int kt=0;kt<8;kt++) a1n[kt] = read_afrag(sh_h1u, col, hi, kt);
      f32x4 hp = {bp1p, bp1p, bp1p, bp1p};
      const unsigned short* tbp = wTp + (size_t)w*4096 + lane*8;
      #pragma unroll
      for (int kt=0;kt<8;kt++){
        hp = MFMA16(a1n[kt], *(const s8v*)(tbp + kt*512), hp);
      }
      #pragma unroll
      for (int q=0;q<4;q++){
        float r  = fmaxf(hp[q], 0.f);
        float s0 = r*w20, s1 = r*w21;
        #pragma unroll
        for (int off=1; off<16; off<<=1){
          s0 += __shfl_xor(s0, off, 64);
          s1 += __shfl_xor(s1, off, 64);
        }
        if (col == 0){ sh_red[w][hi*4+q][0] = s0; sh_red[w][hi*4+q][1] = s1; }
      }
    }
    __syncthreads();

    // ---- P5: combine wave partials, update pos, write out ----
    if (tid < 32){
      int b = tid >> 1, d = tid & 1;
      float s = sh_red[0][b][d] + sh_red[1][b][d] + sh_red[2][b][d] + sh_red[3][b][d]
              + (d ? bp21 : bp20);
      float np = sh_pos[b][d] + s;
      sh_pos[b][d] = np;
      out[((size_t)(gb0+b)*NSTEP + t)*2 + d] = np;
    }
    __syncthreads();
  }
}

extern "C" void kernel_launch(void* const* d_in, const int* in_sizes, int n_in,
                              void* d_out, int out_size, void* d_ws, size_t ws_size,
                              hipStream_t stream) {
  const float* enc  = (const float*)d_in[0];
  const float* pos0 = (const float*)d_in[1];
  const float* ctx  = (const float*)d_in[2];
  const float* Wh   = (const float*)d_in[3];
  const float* bh   = (const float*)d_in[4];
  const float* Wc   = (const float*)d_in[5];
  const float* bc   = (const float*)d_in[6];
  const float* Wih0 = (const float*)d_in[7];
  const float* Whh0 = (const float*)d_in[8];
  const float* bih0 = (const float*)d_in[9];
  const float* bhh0 = (const float*)d_in[10];
  const float* Wih1 = (const float*)d_in[11];
  const float* Whh1 = (const float*)d_in[12];
  const float* bih1 = (const float*)d_in[13];
  const float* bhh1 = (const float*)d_in[14];
  const float* Wp1  = (const float*)d_in[15];
  const float* bp1  = (const float*)d_in[16];
  const float* Wp2  = (const float*)d_in[17];
  const float* bp2  = (const float*)d_in[18];
  float* out = (float*)d_out;
  unsigned short* wsW = (unsigned short*)d_ws;

  // repack weights -> bf16 B-fragment tiles (100352 threads)
  hipLaunchKernelGGL(repack, dim3(392), dim3(256), 0, stream,
                     Whh0, Wih1, Whh1, Wp1, wsW);

  const int B = 4096;
  hipLaunchKernelGGL(traj_mfma, dim3(B / BB), dim3(TPB), 0, stream,
                     enc, pos0, ctx, Wh, bh, Wc, bc, Wih0, bih0, bhh0,
                     bih1, bhh1, Wp2, bp1, bp2, wsW, out);
}

// Round 7
// 4204.967 us; speedup vs baseline: 1.2725x; 1.2725x over previous
//
#include <hip/hip_runtime.h>
#include <hip/hip_bf16.h>

// TrajectoryDecoder: 2-layer LSTM (H=256), 45 steps, B=4096.
// R6: BB=32 (128 WGs x 512 thr). Each weight B-frag loaded once per WG
// feeds TWO batch-quads (2 MFMAs) -> weight demand halved to 9.2 GB.
// 256-VGPR budget + register-array fragment preloads for deep MLP.
// Weights bf16-repacked in d_ws (R5 layout). gctx bf16 in LDS.
// mfma_f32_16x16x32_bf16: A row=lane&15(batch), k=(lane>>4)*8+j;
//   B col=lane&15(gate unit); C/D row=(lane>>4)*4+q, col=lane&15.

#define BB    32
#define TPB   512
#define HN    256
#define DM    128
#define NSTEP 45

typedef __attribute__((ext_vector_type(8))) short s8v;
typedef __attribute__((ext_vector_type(4))) float f32x4;

#define MFMA16(a,b,c) __builtin_amdgcn_mfma_f32_16x16x32_bf16((a),(b),(c),0,0,0)

__device__ __forceinline__ unsigned short f2bf(float f){
  union { float f; unsigned u; } x; x.f = f;
  unsigned r = x.u + 0x7fffu + ((x.u >> 16) & 1u);
  return (unsigned short)(r >> 16);
}
__device__ __forceinline__ float bf2f(unsigned short h){
  union { unsigned u; float f; } x; x.u = ((unsigned)h) << 16;
  return x.f;
}
__device__ __forceinline__ float sigm(float x){
  x = fminf(40.f, fmaxf(-40.f, x));
  return 1.f/(1.f + __expf(-x));
}
__device__ __forceinline__ float tanhx(float x){
  float xx = fminf(15.f, fmaxf(-15.f, x));
  float e = __expf(2.f*xx);
  return (e-1.f)/(e+1.f);
}

// h LDS: bf16 [32 rows][256], row b element u stored at u ^ ((b&7)<<3)
__device__ __forceinline__ void write_h(unsigned short* lds, int b, int u, float v){
  lds[b*HN + (u ^ ((b&7)<<3))] = f2bf(v);
}
__device__ __forceinline__ s8v read_afrag(const unsigned short* lds, int b, int hi, int kt){
  int blk = (kt*4 + hi) ^ (b & 7);
  return *(const s8v*)(lds + b*HN + blk*8);
}

// ---- repack: fp32 row-major -> bf16 B-fragment tiles (same layout as R5) ----
// d_ws (ushort): Whh0[262144] | Wih1[262144] | Whh1[262144] | Wp1[16384]
// tile r=(ut*4+g)*8+kt at r*512+lane*8 holds W[g*256+ut*16+(lane&15)][kt*32+(lane>>4)*8+j]
__global__ void repack(const float* __restrict__ Whh0, const float* __restrict__ Wih1,
                       const float* __restrict__ Whh1, const float* __restrict__ Wp1,
                       unsigned short* __restrict__ dst){
  int gid  = blockIdx.x*256 + threadIdx.x;
  int lane = gid & 63;
  int tile = gid >> 6;
  const float* src; int row; size_t doff;
  int k0 = (lane>>4)*8;
  if (tile < 1536){
    int mi = tile / 512;
    int r  = tile % 512;
    int kt = r & 7;
    int gu = r >> 3;
    int g  = gu & 3, ut = gu >> 2;
    src  = (mi==0) ? Whh0 : (mi==1) ? Wih1 : Whh1;
    row  = g*256 + ut*16 + (lane&15);
    k0  += kt*32;
    doff = (size_t)mi*262144 + (size_t)r*512 + lane*8;
  } else {
    int r2 = tile - 1536;
    int kt = r2 & 7, ut = r2 >> 3;
    src  = Wp1;
    row  = ut*16 + (lane&15);
    k0  += kt*32;
    doff = 786432 + (size_t)r2*512 + lane*8;
  }
  const float* s = src + (size_t)row*HN + k0;
  float4 a = *(const float4*)(s);
  float4 b = *(const float4*)(s+4);
  unsigned short* d = dst + doff;
  d[0]=f2bf(a.x); d[1]=f2bf(a.y); d[2]=f2bf(a.z); d[3]=f2bf(a.w);
  d[4]=f2bf(b.x); d[5]=f2bf(b.y); d[6]=f2bf(b.z); d[7]=f2bf(b.w);
}

__global__ __launch_bounds__(TPB, 2)
void traj_mfma(const float* __restrict__ enc,   // B x 128
               const float* __restrict__ pos0,  // B x 2
               const float* __restrict__ ctx,   // B x 128
               const float* __restrict__ Wh,    // 512 x 128
               const float* __restrict__ bh,
               const float* __restrict__ Wc,
               const float* __restrict__ bc,
               const float* __restrict__ Wih0,  // 1024 x 130
               const float* __restrict__ bih0,
               const float* __restrict__ bhh0,
               const float* __restrict__ bih1,
               const float* __restrict__ bhh1,
               const float* __restrict__ Wp2,   // 2 x 64
               const float* __restrict__ bp1,
               const float* __restrict__ bp2,
               const unsigned short* __restrict__ wsW,
               float* __restrict__ out)         // B x 45 x 2
{
  __shared__ unsigned short sh_h0u[BB*HN];     // 16KB bf16 swizzled
  __shared__ unsigned short sh_h1u[BB*HN];     // 16KB
  __shared__ float sh_x[BB][DM];               // 16KB staging
  __shared__ unsigned char sh_dyn[65536];      // 64KB: ct fp32 [2][32][256] -> gctx bf16 [32][1024]
  __shared__ float sh_pos[BB][2];
  __shared__ float sh_red[4][BB][2];

  const int tid  = threadIdx.x;
  const int gb0  = blockIdx.x * BB;
  const int lane = tid & 63;
  const int w    = tid >> 6;        // 8 waves
  const int col  = lane & 15;
  const int hi   = lane >> 4;

  // ---- stage encoder_feat + pos ----
  {
    const float4* src = (const float4*)(enc + (size_t)gb0*DM);
    float4* dstx = (float4*)&sh_x[0][0];
    dstx[tid] = src[tid];
    dstx[tid+512] = src[tid+512];
  }
  if (tid < BB*2) ((float*)sh_pos)[tid] = pos0[(size_t)gb0*2 + tid];
  __syncthreads();

  // ---- h/c init: thread r computes h_all/c_all row r, 2 passes of 16 batches ----
  {
    float* ct = (float*)sh_dyn;    // [2][32][256]
    const int r = tid;
    const float4* whr = (const float4*)(Wh + (size_t)r*DM);
    const float4* wcr = (const float4*)(Wc + (size_t)r*DM);
    float bhv = bh[r], bcv = bc[r];
    #pragma nounroll
    for (int half=0; half<2; half++){
      float ah[16], ac2[16];
      #pragma unroll
      for (int b=0;b<16;b++){ ah[b]=0.f; ac2[b]=0.f; }
      #pragma nounroll
      for (int kk=0; kk<DM/4; kk++){
        float4 w0 = whr[kk], w1 = wcr[kk];
        #pragma unroll
        for (int b=0;b<16;b++){
          float4 x = *(const float4*)&sh_x[half*16+b][kk*4];
          ah[b]  += w0.x*x.x + w0.y*x.y + w0.z*x.z + w0.w*x.w;
          ac2[b] += w1.x*x.x + w1.y*x.y + w1.z*x.z + w1.w*x.w;
        }
      }
      if (r < HN){
        #pragma unroll
        for (int b=0;b<16;b++){
          write_h(sh_h0u, half*16+b, r, ah[b] + bhv);
          ct[(size_t)(half*16+b)*HN + r] = ac2[b] + bcv;
        }
      } else {
        #pragma unroll
        for (int b=0;b<16;b++){
          write_h(sh_h1u, half*16+b, r-HN, ah[b] + bhv);
          ct[8192 + (size_t)(half*16+b)*HN + (r-HN)] = ac2[b] + bcv;
        }
      }
    }
  }
  __syncthreads();

  // ---- hoist c-state into MFMA-layout registers ----
  float c0r[2][2][4], c1r[2][2][4];   // [m][bq][q]
  {
    const float* ct = (const float*)sh_dyn;
    #pragma unroll
    for (int m=0;m<2;m++){
      int uu = (w*2+m)*16 + col;
      #pragma unroll
      for (int bq=0;bq<2;bq++){
        #pragma unroll
        for (int q=0;q<4;q++){
          int b = bq*16 + hi*4 + q;
          c0r[m][bq][q] = ct[(size_t)b*HN + uu];
          c1r[m][bq][q] = ct[8192 + (size_t)b*HN + uu];
        }
      }
    }
  }
  __syncthreads();   // everyone done reading ct (sh_dyn free)

  // ---- stage context ----
  {
    const float4* src = (const float4*)(ctx + (size_t)gb0*DM);
    float4* dstx = (float4*)&sh_x[0][0];
    dstx[tid] = src[tid];
    dstx[tid+512] = src[tid+512];
  }
  __syncthreads();

  // ---- gates_ctx -> bf16 LDS [32][1024]; thread owns rows tid, tid+512 ----
  {
    unsigned short* gx = (unsigned short*)sh_dyn;
    const float2* wr0 = (const float2*)(Wih0 + (size_t)tid*130 + 2);
    const float2* wr1 = (const float2*)(Wih0 + (size_t)(tid+512)*130 + 2);
    float cb0 = bih0[tid]     + bhh0[tid];
    float cb1 = bih0[tid+512] + bhh0[tid+512];
    #pragma nounroll
    for (int half=0; half<2; half++){
      float a0[16], a1[16];
      #pragma unroll
      for (int b=0;b<16;b++){ a0[b]=0.f; a1[b]=0.f; }
      #pragma nounroll
      for (int kk=0; kk<DM/2; kk++){
        float2 w0 = wr0[kk], w1 = wr1[kk];
        #pragma unroll
        for (int b=0;b<16;b++){
          float2 x = *(const float2*)&sh_x[half*16+b][kk*2];
          a0[b] += w0.x*x.x + w0.y*x.y;
          a1[b] += w1.x*x.x + w1.y*x.y;
        }
      }
      #pragma unroll
      for (int b=0;b<16;b++){
        gx[(size_t)(half*16+b)*1024 + tid]       = f2bf(a0[b] + cb0);
        gx[(size_t)(half*16+b)*1024 + tid + 512] = f2bf(a1[b] + cb1);
      }
    }
  }

  // ---- per-lane constants ----
  float wpr[2][4][2]; float b1r[2][4];
  #pragma unroll
  for (int m=0;m<2;m++){
    int uu = (w*2+m)*16 + col;
    #pragma unroll
    for (int g=0;g<4;g++){
      int j = (g<<8) + uu;
      wpr[m][g][0] = Wih0[(size_t)j*130 + 0];
      wpr[m][g][1] = Wih0[(size_t)j*130 + 1];
      b1r[m][g]    = bih1[j] + bhh1[j];
    }
  }
  const int   p    = (w&3)*16 + col;
  const int   bqh  = w >> 2;
  const float bp1p = bp1[p], w20 = Wp2[p], w21 = Wp2[64+p];
  const float bp20 = bp2[0], bp21 = bp2[1];

  const unsigned short* gx = (const unsigned short*)sh_dyn;
  const unsigned short* wT0 = wsW;            // Whh0
  const unsigned short* wT1 = wsW + 262144;   // Wih1
  const unsigned short* wT2 = wsW + 524288;   // Whh1
  const unsigned short* wTp = wsW + 786432;   // Wp1
  __syncthreads();   // gctx visible

  // ================= 45-step rollout =================
  #pragma nounroll
  for (int t=0; t<NSTEP; t++){
    // ---- P1: A-frags of h0 + pos ----
    s8v A0[2][8];
    #pragma unroll
    for (int bq=0;bq<2;bq++)
      #pragma unroll
      for (int kt=0;kt<8;kt++)
        A0[bq][kt] = read_afrag(sh_h0u, bq*16+col, hi, kt);
    float p0q[2][4], p1q[2][4];
    #pragma unroll
    for (int bq=0;bq<2;bq++)
      #pragma unroll
      for (int q=0;q<4;q++){
        float2 pp = *(const float2*)&sh_pos[bq*16+hi*4+q][0];
        p0q[bq][q]=pp.x; p1q[bq][q]=pp.y;
      }
    __syncthreads();   // all reads of old h0/pos done

    // ---- P2: layer0 gates + cell (each weight frag feeds 2 bq MFMAs) ----
    #pragma unroll
    for (int m=0;m<2;m++){
      const int ut = w*2+m;
      const int uu = ut*16 + col;
      const unsigned short* tb = wT0 + (size_t)(ut*4)*4096 + lane*8;
      s8v wf[32];
      #pragma unroll
      for (int g=0;g<4;g++)
        #pragma unroll
        for (int kt=0;kt<8;kt++)
          wf[g*8+kt] = *(const s8v*)(tb + g*4096 + kt*512);
      f32x4 acc[4][2];
      #pragma unroll
      for (int g=0;g<4;g++)
        #pragma unroll
        for (int bq=0;bq<2;bq++)
          #pragma unroll
          for (int q=0;q<4;q++)
            acc[g][bq][q] = bf2f(gx[(size_t)(bq*16+hi*4+q)*1024 + (g<<8) + uu])
                          + p0q[bq][q]*wpr[m][g][0] + p1q[bq][q]*wpr[m][g][1];
      #pragma unroll
      for (int kt=0;kt<8;kt++)
        #pragma unroll
        for (int g=0;g<4;g++)
          #pragma unroll
          for (int bq=0;bq<2;bq++)
            acc[g][bq] = MFMA16(A0[bq][kt], wf[g*8+kt], acc[g][bq]);
      #pragma unroll
      for (int bq=0;bq<2;bq++)
        #pragma unroll
        for (int q=0;q<4;q++){
          float iv = sigm(acc[0][bq][q]), fv = sigm(acc[1][bq][q]);
          float gv = tanhx(acc[2][bq][q]), ov = sigm(acc[3][bq][q]);
          float cv = fv*c0r[m][bq][q] + iv*gv;
          c0r[m][bq][q] = cv;
          write_h(sh_h0u, bq*16+hi*4+q, uu, ov*tanhx(cv));
        }
    }
    __syncthreads();   // new h0 visible

    // ---- P3: layer1 gates + cell ----
    s8v A0n[2][8], A1[2][8];
    #pragma unroll
    for (int bq=0;bq<2;bq++)
      #pragma unroll
      for (int kt=0;kt<8;kt++){
        A0n[bq][kt] = read_afrag(sh_h0u, bq*16+col, hi, kt);
        A1[bq][kt]  = read_afrag(sh_h1u, bq*16+col, hi, kt);
      }
    __syncthreads();   // all reads of old h1 done
    #pragma unroll
    for (int m=0;m<2;m++){
      const int ut = w*2+m;
      const int uu = ut*16 + col;
      f32x4 acc[4][2];
      #pragma unroll
      for (int g=0;g<4;g++)
        #pragma unroll
        for (int bq=0;bq<2;bq++)
          #pragma unroll
          for (int q=0;q<4;q++)
            acc[g][bq][q] = b1r[m][g];
      {
        const unsigned short* tb1 = wT1 + (size_t)(ut*4)*4096 + lane*8;
        s8v wf[32];
        #pragma unroll
        for (int g=0;g<4;g++)
          #pragma unroll
          for (int kt=0;kt<8;kt++)
            wf[g*8+kt] = *(const s8v*)(tb1 + g*4096 + kt*512);
        #pragma unroll
        for (int kt=0;kt<8;kt++)
          #pragma unroll
          for (int g=0;g<4;g++)
            #pragma unroll
            for (int bq=0;bq<2;bq++)
              acc[g][bq] = MFMA16(A0n[bq][kt], wf[g*8+kt], acc[g][bq]);
      }
      {
        const unsigned short* tb2 = wT2 + (size_t)(ut*4)*4096 + lane*8;
        s8v wf[32];
        #pragma unroll
        for (int g=0;g<4;g++)
          #pragma unroll
          for (int kt=0;kt<8;kt++)
            wf[g*8+kt] = *(const s8v*)(tb2 + g*4096 + kt*512);
        #pragma unroll
        for (int kt=0;kt<8;kt++)
          #pragma unroll
          for (int g=0;g<4;g++)
            #pragma unroll
            for (int bq=0;bq<2;bq++)
              acc[g][bq] = MFMA16(A1[bq][kt], wf[g*8+kt], acc[g][bq]);
      }
      #pragma unroll
      for (int bq=0;bq<2;bq++)
        #pragma unroll
        for (int q=0;q<4;q++){
          float iv = sigm(acc[0][bq][q]), fv = sigm(acc[1][bq][q]);
          float gv = tanhx(acc[2][bq][q]), ov = sigm(acc[3][bq][q]);
          float cv = fv*c1r[m][bq][q] + iv*gv;
          c1r[m][bq][q] = cv;
          write_h(sh_h1u, bq*16+hi*4+q, uu, ov*tanhx(cv));
        }
    }
    __syncthreads();   // new h1 visible

    // ---- P4: head — wave (w&3) owns p-tile, (w>>2) owns batch-quad ----
    {
      s8v A1n[8], wfp[8];
      const unsigned short* tbp = wTp + (size_t)(w&3)*4096 + lane*8;
      #pragma unroll
      for (int kt=0;kt<8;kt++){
        A1n[kt] = read_afrag(sh_h1u, bqh*16+col, hi, kt);
        wfp[kt] = *(const s8v*)(tbp + kt*512);
      }
      f32x4 hp = {bp1p, bp1p, bp1p, bp1p};
      #pragma unroll
      for (int kt=0;kt<8;kt++)
        hp = MFMA16(A1n[kt], wfp[kt], hp);
      #pragma unroll
      for (int q=0;q<4;q++){
        float r  = fmaxf(hp[q], 0.f);
        float s0 = r*w20, s1 = r*w21;
        #pragma unroll
        for (int off=1; off<16; off<<=1){
          s0 += __shfl_xor(s0, off, 64);
          s1 += __shfl_xor(s1, off, 64);
        }
        if (col == 0){
          sh_red[w&3][bqh*16+hi*4+q][0] = s0;
          sh_red[w&3][bqh*16+hi*4+q][1] = s1;
        }
      }
    }
    __syncthreads();   // sh_red complete

    // ---- P5: combine partials, update pos, write out ----
    if (tid < BB*2){
      int b = tid >> 1, d = tid & 1;
      float s = sh_red[0][b][d] + sh_red[1][b][d] + sh_red[2][b][d] + sh_red[3][b][d]
              + (d ? bp21 : bp20);
      float np = sh_pos[b][d] + s;
      sh_pos[b][d] = np;
      out[((size_t)(gb0+b)*NSTEP + t)*2 + d] = np;
    }
    __syncthreads();   // pos stable for next step
  }
}

extern "C" void kernel_launch(void* const* d_in, const int* in_sizes, int n_in,
                              void* d_out, int out_size, void* d_ws, size_t ws_size,
                              hipStream_t stream) {
  const float* enc  = (const float*)d_in[0];
  const float* pos0 = (const float*)d_in[1];
  const float* ctx  = (const float*)d_in[2];
  const float* Wh   = (const float*)d_in[3];
  const float* bh   = (const float*)d_in[4];
  const float* Wc   = (const float*)d_in[5];
  const float* bc   = (const float*)d_in[6];
  const float* Wih0 = (const float*)d_in[7];
  const float* Whh0 = (const float*)d_in[8];
  const float* bih0 = (const float*)d_in[9];
  const float* bhh0 = (const float*)d_in[10];
  const float* Wih1 = (const float*)d_in[11];
  const float* Whh1 = (const float*)d_in[12];
  const float* bih1 = (const float*)d_in[13];
  const float* bhh1 = (const float*)d_in[14];
  const float* Wp1  = (const float*)d_in[15];
  const float* bp1  = (const float*)d_in[16];
  const float* Wp2  = (const float*)d_in[17];
  const float* bp2  = (const float*)d_in[18];
  float* out = (float*)d_out;
  unsigned short* wsW = (unsigned short*)d_ws;

  hipLaunchKernelGGL(repack, dim3(392), dim3(256), 0, stream,
                     Whh0, Wih1, Whh1, Wp1, wsW);

  const int B = 4096;
  hipLaunchKernelGGL(traj_mfma, dim3(B / BB), dim3(TPB), 0, stream,
                     enc, pos0, ctx, Wh, bh, Wc, bc, Wih0, bih0, bhh0,
                     bih1, bhh1, Wp2, bp1, bp2, wsW, out);
}